// Round 1
// baseline (27839.062 us; speedup 1.0000x reference)
//
#include <hip/hip_runtime.h>
#include <hip/hip_cooperative_groups.h>

namespace cg = cooperative_groups;

#define B_  64
#define F_  128
#define H_  512
#define S_  512
#define T_  96
#define G3  1536   // 3*H
#define KIH 640    // F+H

// ---- workspace layout (float offsets) ----
#define ENC_OFF 0
#define ENC_SZ  (B_*S_*H_)          // 16777216 floats (64 MB)
#define HT_OFF  (ENC_OFF + ENC_SZ)  // hT[k][b]
#define HT_SZ   (H_*B_)
#define XT_OFF  (HT_OFF + HT_SZ)    // xT[f][b]
#define XT_SZ   (F_*B_)
#define HP_OFF  (XT_OFF + XT_SZ)    // hprojT[h][b]
#define HP_SZ   (H_*B_)
#define GH_OFF  (HP_OFF + HP_SZ)    // ghT[n][b]  (includes b_hh)
#define GH_SZ   (G3*B_)
#define GX_OFF  (GH_OFF + GH_SZ)    // gx_xT[n][b] (x part only, no bias)
#define GX_SZ   (G3*B_)
#define SC_OFF  (GX_OFF + GX_SZ)    // scores[b][s]
#define SC_SZ   (B_*S_)
#define WT_OFF  (SC_OFF + SC_SZ)    // weightedT[h][b]
#define WT_SZ   (H_*B_)

#define NB 256
#define NT 512

struct Params {
  const float* dec_input;
  const float* hidden;
  const float* enc;
  const float* Wa;
  const float* Wv;
  const float* Wih;
  const float* bih;
  const float* Whh;
  const float* bhh;
  const float* Wout;
  const float* bout;
  float* ws;
  float* out;
};

__device__ __forceinline__ float fast_tanh(float x) {
  float e2 = __expf(2.f * x);
  return 1.f - 2.f / (e2 + 1.f);
}
__device__ __forceinline__ float fast_sig(float x) {
  return 1.f / (1.f + __expf(-x));
}

// ---------------- EncProj = enc @ Wa[:,H:].T + ba  (one-time) ----------------
// C[m][n], m = b*S+s (M=32768), n<512, K=512. A=enc row-major, B=Wa rows (stride 2H).
__global__ __launch_bounds__(256) void encproj_kernel(
    const float* __restrict__ enc, const float* __restrict__ Wa,
    const float* __restrict__ ba, float* __restrict__ EncProj) {
  __shared__ float As[16][64];  // [k][m]
  __shared__ float Bs[16][64];  // [k][n]
  const int m0 = blockIdx.x * 64, n0 = blockIdx.y * 64;
  const int tid = threadIdx.x;
  const int tr = tid >> 4, tc = tid & 15;
  float acc[4][4] = {};
  for (int k0 = 0; k0 < H_; k0 += 16) {
    #pragma unroll
    for (int r = 0; r < 4; ++r) {
      int mm = (tid >> 4) + r * 16;
      As[tid & 15][mm] = enc[(size_t)(m0 + mm) * H_ + k0 + (tid & 15)];
      Bs[tid & 15][mm] = Wa[(size_t)(n0 + mm) * (2 * H_) + H_ + k0 + (tid & 15)];
    }
    __syncthreads();
    #pragma unroll
    for (int kk = 0; kk < 16; ++kk) {
      float a[4], b[4];
      #pragma unroll
      for (int i = 0; i < 4; ++i) a[i] = As[kk][tr * 4 + i];
      #pragma unroll
      for (int i = 0; i < 4; ++i) b[i] = Bs[kk][tc * 4 + i];
      #pragma unroll
      for (int i = 0; i < 4; ++i)
        #pragma unroll
        for (int j = 0; j < 4; ++j) acc[i][j] += a[i] * b[j];
    }
    __syncthreads();
  }
  #pragma unroll
  for (int i = 0; i < 4; ++i)
    #pragma unroll
    for (int j = 0; j < 4; ++j)
      EncProj[(size_t)(m0 + tr * 4 + i) * H_ + n0 + tc * 4 + j] =
          acc[i][j] + ba[n0 + tc * 4 + j];
}

// ---- P6: from h (=h_new) compute out/x, hprojT, ghT. All K=512 dot products. ----
__device__ void phase6(const Params& p, float* hT, float* xT, float* hpT,
                       float* ghT, int t, bool do_out, int flat) {
  for (int idx = flat; idx < (F_ + H_ + G3) * B_; idx += NB * NT) {
    int n = idx >> 6, b = idx & 63;
    const float* wrow;
    if (n < F_) {
      if (!do_out) continue;
      wrow = p.Wout + (size_t)n * H_;
    } else if (n < F_ + H_) {
      wrow = p.Wa + (size_t)(n - F_) * (2 * H_);   // Wa[:, :H] row
    } else {
      wrow = p.Whh + (size_t)(n - F_ - H_) * H_;
    }
    float acc = 0.f;
    #pragma unroll 4
    for (int k = 0; k < H_; ++k) acc += hT[k * B_ + b] * wrow[k];
    if (n < F_) {
      acc += p.bout[n];
      p.out[(size_t)b * (T_ * F_) + (size_t)t * F_ + n] = acc;
      xT[n * B_ + b] = acc;
    } else if (n < F_ + H_) {
      hpT[(n - F_) * B_ + b] = acc;
    } else {
      int m = n - F_ - H_;
      ghT[m * B_ + b] = acc + p.bhh[m];
    }
  }
}

__global__ __launch_bounds__(NT, 2) void decoder_kernel(Params p) {
  cg::grid_group grid = cg::this_grid();
  float* ENCP = p.ws + ENC_OFF;
  float* hT = p.ws + HT_OFF;
  float* xT = p.ws + XT_OFF;
  float* hpT = p.ws + HP_OFF;
  float* ghT = p.ws + GH_OFF;
  float* gxT = p.ws + GX_OFF;
  float* sc = p.ws + SC_OFF;
  float* wT = p.ws + WT_OFF;

  const int tid = threadIdx.x;
  const int bid = blockIdx.x;
  const int flat = bid * NT + tid;

  __shared__ float lds[1544];

  // ---- P0a: transposed copies of initial h and x ----
  if (flat < H_ * B_) {
    int b = flat >> 9, k = flat & 511;
    hT[k * B_ + b] = p.hidden[flat];
  } else if (flat < H_ * B_ + F_ * B_) {
    int q = flat - H_ * B_;
    int b = q >> 7, f = q & 127;
    xT[f * B_ + b] = p.dec_input[q];
  }
  grid.sync();
  // ---- P0b: hprojT, ghT from h0 ----
  phase6(p, hT, xT, hpT, ghT, 0, false, flat);
  grid.sync();

  for (int t = 0; t < T_; ++t) {
    // ---- P2: scores[b][s] = sum_h Wv[h]*tanh(hproj[b][h]+EncProj[b][s][h]); gx_x ----
    {
      const int wave = flat >> 6;       // 0..2047
      const int lane = tid & 63;
      const int b = wave >> 5;          // 32 waves per batch row
      const int s0 = (wave & 31) << 4;  // 16 s per wave
      float hp[8], wv[8];
      #pragma unroll
      for (int j = 0; j < 8; ++j) {
        int h = lane + j * 64;
        hp[j] = hpT[h * B_ + b];
        wv[j] = p.Wv[h];
      }
      const float* epb = ENCP + (size_t)b * (S_ * H_);
      for (int i = 0; i < 16; ++i) {
        const float* ep = epb + (size_t)(s0 + i) * H_;
        float acc = 0.f;
        #pragma unroll
        for (int j = 0; j < 8; ++j) {
          float v = hp[j] + ep[lane + j * 64];
          acc += wv[j] * fast_tanh(v);
        }
        #pragma unroll
        for (int off = 32; off; off >>= 1) acc += __shfl_xor(acc, off, 64);
        if (lane == 0) sc[b * S_ + s0 + i] = acc;
      }
      if (flat < G3 * B_) {  // gx_x[n][b] = sum_f x[b][f]*Wih[n][f]
        int n = flat >> 6, bb = flat & 63;
        const float* w = p.Wih + (size_t)n * KIH;
        float a = 0.f;
        #pragma unroll 4
        for (int k = 0; k < F_; ++k) a += xT[k * B_ + bb] * w[k];
        gxT[n * B_ + bb] = a;
      }
    }
    grid.sync();
    // ---- P4: fused softmax + weighted context -> weightedT[h][b] ----
    {
      const int b = bid >> 2, ch = bid & 3;
      lds[tid] = __expf(sc[b * S_ + tid]);  // scores bounded (|s|<=~11): safe
      __syncthreads();
      if (tid < 64) {
        float d = 0.f;
        #pragma unroll
        for (int j = 0; j < 8; ++j) d += lds[tid + j * 64];
        #pragma unroll
        for (int off = 32; off; off >>= 1) d += __shfl_xor(d, off, 64);
        if (tid == 0) lds[1536] = d;
      }
      __syncthreads();
      const float den = lds[1536];
      const int hl = tid & 127, sq = tid >> 7;
      const int hh = ch * 128 + hl;
      const float* encb = p.enc + (size_t)b * (S_ * H_) + hh;
      float acc = 0.f;
      for (int s = sq * 128; s < sq * 128 + 128; ++s)
        acc += lds[s] * encb[(size_t)s * H_];
      lds[512 + tid] = acc;
      __syncthreads();
      if (tid < 128) {
        float v = lds[512 + tid] + lds[512 + tid + 128] + lds[512 + tid + 256] +
                  lds[512 + tid + 384];
        wT[(ch * 128 + tid) * B_ + b] = v / den;
      }
    }
    grid.sync();
    // ---- P5: GRU gates -> hT (in place) ----
    {
      const int b = tid & 63, jl = (tid >> 6) & 1, kq = tid >> 7;
      const int j = bid * 2 + jl;
      const float* wr = p.Wih + (size_t)j * KIH + F_;
      const float* wz = p.Wih + (size_t)(H_ + j) * KIH + F_;
      const float* wn = p.Wih + (size_t)(2 * H_ + j) * KIH + F_;
      float ar = 0.f, az = 0.f, an = 0.f;
      for (int k = kq * 128; k < kq * 128 + 128; ++k) {
        float a = wT[k * B_ + b];
        ar += a * wr[k];
        az += a * wz[k];
        an += a * wn[k];
      }
      lds[((jl * 3 + 0) * 4 + kq) * 64 + b] = ar;
      lds[((jl * 3 + 1) * 4 + kq) * 64 + b] = az;
      lds[((jl * 3 + 2) * 4 + kq) * 64 + b] = an;
      __syncthreads();
      if (kq == 0) {
        float gxr = gxT[j * B_ + b] + p.bih[j];
        float gxz = gxT[(H_ + j) * B_ + b] + p.bih[H_ + j];
        float gxn = gxT[(2 * H_ + j) * B_ + b] + p.bih[2 * H_ + j];
        #pragma unroll
        for (int q = 0; q < 4; ++q) {
          gxr += lds[((jl * 3 + 0) * 4 + q) * 64 + b];
          gxz += lds[((jl * 3 + 1) * 4 + q) * 64 + b];
          gxn += lds[((jl * 3 + 2) * 4 + q) * 64 + b];
        }
        float r = fast_sig(gxr + ghT[j * B_ + b]);
        float z = fast_sig(gxz + ghT[(H_ + j) * B_ + b]);
        float nn = fast_tanh(gxn + r * ghT[(2 * H_ + j) * B_ + b]);
        float h = hT[j * B_ + b];
        hT[j * B_ + b] = (1.f - z) * nn + z * h;
      }
    }
    grid.sync();
    // ---- P6: out (+x for next step), hprojT, ghT from h_new ----
    phase6(p, hT, xT, hpT, ghT, t, true, flat);
    grid.sync();
  }
}

extern "C" void kernel_launch(void* const* d_in, const int* in_sizes, int n_in,
                              void* d_out, int out_size, void* d_ws, size_t ws_size,
                              hipStream_t stream) {
  Params p;
  p.dec_input = (const float*)d_in[0];
  p.hidden = (const float*)d_in[1];
  p.enc = (const float*)d_in[2];
  // d_in[3] expected_outputs (unused), d_in[4] dec_output_len (fixed 96)
  p.Wa = (const float*)d_in[5];
  const float* ba = (const float*)d_in[6];
  p.Wv = (const float*)d_in[7];
  // d_in[8] bv: constant shift, cancels in softmax
  p.Wih = (const float*)d_in[9];
  p.bih = (const float*)d_in[10];
  p.Whh = (const float*)d_in[11];
  p.bhh = (const float*)d_in[12];
  p.Wout = (const float*)d_in[13];
  p.bout = (const float*)d_in[14];
  p.ws = (float*)d_ws;
  p.out = (float*)d_out;

  dim3 g1(512, 8), b1(256);
  hipLaunchKernelGGL(encproj_kernel, g1, b1, 0, stream, p.enc, p.Wa, ba,
                     p.ws + ENC_OFF);

  void* args[] = {&p};
  hipLaunchCooperativeKernel((void*)decoder_kernel, dim3(NB), dim3(NT), args, 0,
                             stream);
}

// Round 2
// 18553.044 us; speedup vs baseline: 1.5005x; 1.5005x over previous
//
#include <hip/hip_runtime.h>

typedef unsigned short u16;
typedef u16 u16x8 __attribute__((ext_vector_type(8)));

#define B_   64
#define F_   128
#define H_   512
#define S_   512
#define T_   96
#define G3   1536
#define KIH  640
#define NBLK 256
#define NTHR 1024
#define NROWS (F_ + H_ + G3)   // 2176

// ---- workspace byte offsets ----
#define BAR_OFF   0ul
#define HT2_OFF   256ul                      // f32 [64][512]   h (row-major per batch)
#define XT_OFF    (HT2_OFF + 131072ul)       // f32 [128][64]   x transposed
#define HPT2_OFF  (XT_OFF + 32768ul)         // f32 [64][512]   h@Wa1^T
#define GHT_OFF   (HPT2_OFF + 131072ul)      // f32 [1536][64]  h@Whh^T + bhh
#define GXT_OFF   (GHT_OFF + 393216ul)       // f32 [1536][64]  x@Wih_x^T
#define SC_OFF    (GXT_OFF + 393216ul)       // f32 [64][512]   scores
#define ENCP_OFF  1213440ul                  // u16 [64][512][512]  enc@Wa2^T + ba
#define ENCW_OFF  (ENCP_OFF + 33554432ul)    // u16 [64][1536][512] (enc@Wih_h^T)^T per b
// total ws needed: 135431168 bytes (~129.2 MiB)

struct Params {
  const float *dec_input, *hidden, *Wa, *Wv, *Wih, *bih, *Whh, *bhh, *Wout, *bout;
  char* ws;
  float* out;
};

__device__ __forceinline__ float fast_tanh(float x) {
  float e2 = __expf(2.f * x);
  return 1.f - 2.f / (e2 + 1.f);
}
__device__ __forceinline__ float fast_sig(float x) { return 1.f / (1.f + __expf(-x)); }
__device__ __forceinline__ float bf2f(u16 u) {
  return __uint_as_float(((unsigned)u) << 16);
}
__device__ __forceinline__ u16 f2bf(float f) {
  unsigned u = __float_as_uint(f);
  return (u16)((u + 0x7fffu + ((u >> 16) & 1u)) >> 16);
}

// ---------------- one-time GEMM: out[z][m][n] = sum_k A[z][m][k]*B[z][n][k] (+bias[n]), bf16 out ----
__global__ __launch_bounds__(256) void gemm_bt_bf16(
    const float* __restrict__ A, long aZ, int lda,
    const float* __restrict__ Bm, long bZ, int ldb,
    const float* __restrict__ bias, u16* __restrict__ out, long oZ, int ldo) {
  __shared__ float As[16][64];
  __shared__ float Bs[16][64];
  const int z = blockIdx.z;
  A += (long)z * aZ; Bm += (long)z * bZ; out += (long)z * oZ;
  const int m0 = blockIdx.x * 64, n0 = blockIdx.y * 64;
  const int tid = threadIdx.x;
  const int tr = tid >> 4, tc = tid & 15;
  const int kk_ = tid & 15, mm_ = tid >> 4;
  float acc[4][4] = {};
  for (int k0 = 0; k0 < 512; k0 += 16) {
    #pragma unroll
    for (int r = 0; r < 4; ++r) {
      int mm = mm_ + r * 16;
      As[kk_][mm] = A[(size_t)(m0 + mm) * lda + k0 + kk_];
      Bs[kk_][mm] = Bm[(size_t)(n0 + mm) * ldb + k0 + kk_];
    }
    __syncthreads();
    #pragma unroll
    for (int kk = 0; kk < 16; ++kk) {
      float av[4], bv[4];
      #pragma unroll
      for (int i = 0; i < 4; ++i) av[i] = As[kk][tr * 4 + i];
      #pragma unroll
      for (int i = 0; i < 4; ++i) bv[i] = Bs[kk][tc * 4 + i];
      #pragma unroll
      for (int i = 0; i < 4; ++i)
        #pragma unroll
        for (int j = 0; j < 4; ++j) acc[i][j] += av[i] * bv[j];
    }
    __syncthreads();
  }
  #pragma unroll
  for (int i = 0; i < 4; ++i)
    #pragma unroll
    for (int j = 0; j < 4; ++j) {
      float v = acc[i][j] + (bias ? bias[n0 + tc * 4 + j] : 0.f);
      out[(size_t)(m0 + tr * 4 + i) * ldo + n0 + tc * 4 + j] = f2bf(v);
    }
}

// ---------------- custom grid barrier ----------------
__device__ __forceinline__ void gridbar(unsigned* cnt, unsigned* gen) {
  __syncthreads();
  if (threadIdx.x == 0) {
    __threadfence();  // release prior global writes (agent scope)
    unsigned g = __hip_atomic_load(gen, __ATOMIC_RELAXED, __HIP_MEMORY_SCOPE_AGENT);
    unsigned a = __hip_atomic_fetch_add(cnt, 1u, __ATOMIC_RELAXED, __HIP_MEMORY_SCOPE_AGENT);
    if (a == NBLK - 1) {
      __hip_atomic_store(cnt, 0u, __ATOMIC_RELAXED, __HIP_MEMORY_SCOPE_AGENT);
      __hip_atomic_store(gen, g + 1u, __ATOMIC_RELEASE, __HIP_MEMORY_SCOPE_AGENT);
    } else {
      while (__hip_atomic_load(gen, __ATOMIC_RELAXED, __HIP_MEMORY_SCOPE_AGENT) == g)
        __builtin_amdgcn_s_sleep(2);
    }
    __threadfence();  // acquire
  }
  __syncthreads();
}

__global__ __launch_bounds__(NTHR, 4) void decoder_kernel(Params p) {
  float* HT2  = (float*)(p.ws + HT2_OFF);
  float* XT   = (float*)(p.ws + XT_OFF);
  float* HPT2 = (float*)(p.ws + HPT2_OFF);
  float* GHT  = (float*)(p.ws + GHT_OFF);
  float* GXT  = (float*)(p.ws + GXT_OFF);
  float* SC   = (float*)(p.ws + SC_OFF);
  const u16* ENCPB = (const u16*)(p.ws + ENCP_OFF);
  const u16* ENCWB = (const u16*)(p.ws + ENCW_OFF);
  unsigned* cnt = (unsigned*)(p.ws + BAR_OFF);
  unsigned* gen = (unsigned*)(p.ws + BAR_OFF + 64);

  const int tid = threadIdx.x;
  const int bid = blockIdx.x;
  const int flat = (bid << 10) + tid;
  const int lane = tid & 63;

  __shared__ float lds[1024];  // [0,512): e[s]; [512,896): gw[384]; [896]: den

  // ---- P0: init hT (row-major) and xT (transposed) ----
  for (int i = flat; i < H_ * B_; i += NBLK * NTHR) HT2[i] = p.hidden[i];
  if (flat < F_ * B_) {
    int b = flat >> 7, f = flat & 127;
    XT[(f << 6) + b] = p.dec_input[flat];
  }
  gridbar(cnt, gen);

  // ---- phase C as a lambda: dots from h -> out/x, hproj, gh ----
  auto phaseC = [&](bool do_out, int t) {
    if (flat < NROWS * B_) {
      const int n = flat >> 6, b = flat & 63;
      if (do_out || n >= F_) {
        const float* wrow;
        if (n < F_) wrow = p.Wout + (size_t)n * H_;
        else if (n < F_ + H_) wrow = p.Wa + (size_t)(n - F_) * (2 * H_);
        else wrow = p.Whh + (size_t)(n - F_ - H_) * H_;
        const float4* h4 = (const float4*)(HT2 + (b << 9));
        const float4* w4 = (const float4*)wrow;
        float acc = 0.f;
        #pragma unroll 8
        for (int k = 0; k < 128; ++k) {
          float4 a = h4[k], c = w4[k];
          acc += a.x * c.x + a.y * c.y + a.z * c.z + a.w * c.w;
        }
        if (n < F_) {
          acc += p.bout[n];
          p.out[((size_t)b * T_ + t) * F_ + n] = acc;
          XT[(n << 6) + b] = acc;
        } else if (n < F_ + H_) {
          HPT2[(b << 9) + (n - F_)] = acc;
        } else {
          GHT[((n - F_ - H_) << 6) + b] = acc + p.bhh[n - F_ - H_];
        }
      }
    }
  };

  phaseC(false, 0);
  gridbar(cnt, gen);

  for (int t = 0; t < T_; ++t) {
    // ---- phase A: scores (bf16 ENCP, 16B/lane) + gx (x-part of gates) ----
    {
      const int wid = (bid << 4) + (tid >> 6);
      const int b = wid >> 6;
      const int s0 = (wid & 63) << 3;
      const float* hpb = HPT2 + (b << 9) + (lane << 3);
      float hp[8], wv[8];
      *(float4*)hp       = *(const float4*)hpb;
      *(float4*)(hp + 4) = *(const float4*)(hpb + 4);
      *(float4*)wv       = *(const float4*)(p.Wv + (lane << 3));
      *(float4*)(wv + 4) = *(const float4*)(p.Wv + (lane << 3) + 4);
      const u16* base = ENCPB + (((size_t)(b << 9) + s0) << 9) + (lane << 3);
      #pragma unroll
      for (int i = 0; i < 8; ++i) {
        u16x8 rv = *(const u16x8*)(base + ((size_t)i << 9));
        float acc = 0.f;
        #pragma unroll
        for (int r = 0; r < 8; ++r)
          acc += wv[r] * fast_tanh(hp[r] + bf2f(rv[r]));
        #pragma unroll
        for (int off = 32; off; off >>= 1) acc += __shfl_xor(acc, off);
        if (lane == 0) SC[(b << 9) + s0 + i] = acc;
      }
      if (flat < G3 * B_) {
        const int n = flat >> 6, bb = flat & 63;
        const float* w = p.Wih + (size_t)n * KIH;
        float a = 0.f;
        #pragma unroll 8
        for (int k = 0; k < F_; ++k) a += XT[(k << 6) + bb] * w[k];
        GXT[(n << 6) + bb] = a;
      }
    }
    gridbar(cnt, gen);

    // ---- phase B (per-batch): softmax + gate-context sums + GRU update ----
    {
      const int b = bid >> 2, q = bid & 3;
      if (tid < 512) lds[tid] = __expf(SC[(b << 9) + tid]);
      __syncthreads();
      if (tid < 64) {
        float d = 0.f;
        #pragma unroll
        for (int r = 0; r < 8; ++r) d += lds[tid + (r << 6)];
        #pragma unroll
        for (int off = 32; off; off >>= 1) d += __shfl_xor(d, off);
        if (tid == 0) lds[896] = d;
      }
      __syncthreads();
      float ev[8];
      #pragma unroll
      for (int r = 0; r < 8; ++r) ev[r] = lds[(lane << 3) + r];
      const int w = tid >> 6;
      for (int i = 0; i < 24; ++i) {
        const int o = w * 24 + i;
        const int g = o >> 7, u = o & 127;
        const int j = (g << 9) + (q << 7) + u;
        u16x8 rv = *(const u16x8*)(ENCWB + (((size_t)b * G3 + j) << 9) + (lane << 3));
        float acc = 0.f;
        #pragma unroll
        for (int r = 0; r < 8; ++r) acc += ev[r] * bf2f(rv[r]);
        #pragma unroll
        for (int off = 32; off; off >>= 1) acc += __shfl_xor(acc, off);
        if (lane == 0) lds[512 + o] = acc;
      }
      __syncthreads();
      if (tid < 128) {
        const int jg = (q << 7) + tid;
        const float inv = 1.f / lds[896];
        float grv = lds[512 + tid] * inv + GXT[(jg << 6) + b] + p.bih[jg] +
                    GHT[(jg << 6) + b];
        float gzv = lds[640 + tid] * inv + GXT[((512 + jg) << 6) + b] +
                    p.bih[512 + jg] + GHT[((512 + jg) << 6) + b];
        float gnx = lds[768 + tid] * inv + GXT[((1024 + jg) << 6) + b] +
                    p.bih[1024 + jg];
        float r = fast_sig(grv), z = fast_sig(gzv);
        float nn = fast_tanh(gnx + r * GHT[((1024 + jg) << 6) + b]);
        float* hp_ = HT2 + (b << 9) + jg;
        *hp_ = (1.f - z) * nn + z * (*hp_);
      }
    }
    gridbar(cnt, gen);

    // ---- phase C: projections from h_new ----
    phaseC(true, t);
    gridbar(cnt, gen);
  }
}

extern "C" void kernel_launch(void* const* d_in, const int* in_sizes, int n_in,
                              void* d_out, int out_size, void* d_ws, size_t ws_size,
                              hipStream_t stream) {
  Params p;
  p.dec_input = (const float*)d_in[0];
  p.hidden    = (const float*)d_in[1];
  const float* enc = (const float*)d_in[2];
  // d_in[3] expected_outputs (unused), d_in[4] dec_output_len (fixed 96)
  p.Wa  = (const float*)d_in[5];
  const float* ba = (const float*)d_in[6];
  p.Wv  = (const float*)d_in[7];
  // d_in[8] bv: constant shift, cancels in softmax
  p.Wih = (const float*)d_in[9];
  p.bih = (const float*)d_in[10];
  p.Whh = (const float*)d_in[11];
  p.bhh = (const float*)d_in[12];
  p.Wout = (const float*)d_in[13];
  p.bout = (const float*)d_in[14];
  p.ws  = (char*)d_ws;
  p.out = (float*)d_out;

  // barrier state must start at 0 (ws is poisoned 0xAA once)
  hipMemsetAsync(d_ws, 0, 256, stream);

  u16* ENCPB = (u16*)((char*)d_ws + ENCP_OFF);
  u16* ENCWB = (u16*)((char*)d_ws + ENCW_OFF);

  // ENCP[b][s][h] = enc[b] @ Wa[:,H:]^T + ba   (bf16)
  hipLaunchKernelGGL(gemm_bt_bf16, dim3(8, 8, 64), dim3(256), 0, stream,
                     enc, (long)(S_ * H_), H_,
                     p.Wa + H_, 0l, 2 * H_,
                     ba, ENCPB, (long)(S_ * H_), H_);
  // ENCWT[b][j][s] = Wih[:,F:] @ enc[b]^T      (bf16, s-contiguous)
  hipLaunchKernelGGL(gemm_bt_bf16, dim3(24, 8, 64), dim3(256), 0, stream,
                     p.Wih + F_, 0l, KIH,
                     enc, (long)(S_ * H_), H_,
                     (const float*)nullptr, ENCWB, (long)(G3 * S_), S_);

  void* args[] = {&p};
  hipLaunchCooperativeKernel((void*)decoder_kernel, dim3(NBLK), dim3(NTHR), args,
                             0, stream);
}

// Round 3
// 9249.405 us; speedup vs baseline: 3.0098x; 2.0059x over previous
//
#include <hip/hip_runtime.h>

typedef unsigned short u16;
typedef u16 u16x8 __attribute__((ext_vector_type(8)));
typedef u16 u16x4 __attribute__((ext_vector_type(4)));

#define B_   64
#define F_   128
#define H_   512
#define S_   512
#define T_   96
#define KIH  640

// ---- workspace byte offsets ----
#define HTC_OFF   0ul            // f32 [512][64]  h transposed (j-major)
#define XT_OFF    131072ul       // f32 [128][64]  x transposed
#define HPT2_OFF  163840ul       // f32 [64][512]  h@Wa1^T (b-major rows)
#define GHT_OFF   294912ul       // f32 [1536][64] h@Whh^T + bhh
#define CT_OFF    688128ul       // f32 [512][64]  context transposed
#define SC_OFF    819200ul       // f32 [64][512]  scores
#define ENCP_OFF  950272ul       // u16 [64][512][512] enc@Wa2^T + ba
#define ENCB_OFF  34504704ul     // u16 [64][512][512] enc in bf16
// end: 68059136 bytes (~65 MiB)

__device__ __forceinline__ float bf2f(u16 u) {
  return __uint_as_float(((unsigned)u) << 16);
}
__device__ __forceinline__ u16 f2bf(float f) {
  unsigned u = __float_as_uint(f);
  return (u16)((u + 0x7fffu + ((u >> 16) & 1u)) >> 16);
}
__device__ __forceinline__ float fast_tanh(float x) {
  float e2 = __expf(2.f * x);
  return 1.f - 2.f / (e2 + 1.f);
}
__device__ __forceinline__ float fast_sig(float x) { return 1.f / (1.f + __expf(-x)); }

// ---------------- enc f32 -> bf16 transcode (one-time) ----------------
__global__ __launch_bounds__(256) void transcode_enc(const float* __restrict__ enc,
                                                     u16* __restrict__ out) {
  int i = blockIdx.x * 256 + threadIdx.x;  // float4 index
  #pragma unroll
  for (int u = 0; u < 4; ++u) {
    int idx = i + u * 1048576;
    float4 v = ((const float4*)enc)[idx];
    u16x4 o;
    o[0] = f2bf(v.x); o[1] = f2bf(v.y); o[2] = f2bf(v.z); o[3] = f2bf(v.w);
    ((u16x4*)out)[idx] = o;
  }
}

// ------------- one-time GEMM: out[z][m][n] = A[z][m]·B[n] (+bias), bf16 out -------------
__global__ __launch_bounds__(256) void gemm_bt_bf16(
    const float* __restrict__ A, long aZ, int lda,
    const float* __restrict__ Bm, int ldb,
    const float* __restrict__ bias, u16* __restrict__ out, long oZ, int ldo) {
  __shared__ float As[16][64];
  __shared__ float Bs[16][64];
  const int z = blockIdx.z;
  A += (long)z * aZ; out += (long)z * oZ;
  const int m0 = blockIdx.x * 64, n0 = blockIdx.y * 64;
  const int tid = threadIdx.x;
  const int tr = tid >> 4, tc = tid & 15;
  const int kk_ = tid & 15, mm_ = tid >> 4;
  float acc[4][4] = {};
  for (int k0 = 0; k0 < 512; k0 += 16) {
    #pragma unroll
    for (int r = 0; r < 4; ++r) {
      int mm = mm_ + r * 16;
      As[kk_][mm] = A[(size_t)(m0 + mm) * lda + k0 + kk_];
      Bs[kk_][mm] = Bm[(size_t)(n0 + mm) * ldb + k0 + kk_];
    }
    __syncthreads();
    #pragma unroll
    for (int kk = 0; kk < 16; ++kk) {
      float av[4], bv[4];
      #pragma unroll
      for (int i = 0; i < 4; ++i) av[i] = As[kk][tr * 4 + i];
      #pragma unroll
      for (int i = 0; i < 4; ++i) bv[i] = Bs[kk][tc * 4 + i];
      #pragma unroll
      for (int i = 0; i < 4; ++i)
        #pragma unroll
        for (int j = 0; j < 4; ++j) acc[i][j] += av[i] * bv[j];
    }
    __syncthreads();
  }
  #pragma unroll
  for (int i = 0; i < 4; ++i)
    #pragma unroll
    for (int j = 0; j < 4; ++j) {
      float v = acc[i][j] + (bias ? bias[n0 + tc * 4 + j] : 0.f);
      out[(size_t)(m0 + tr * 4 + i) * ldo + n0 + tc * 4 + j] = f2bf(v);
    }
}

// ---------------- init: hidden -> HTC (transposed), dec_input -> XT ----------------
__global__ __launch_bounds__(256) void k0_init(const float* __restrict__ hidden,
                                               const float* __restrict__ dec_input,
                                               float* __restrict__ HTC,
                                               float* __restrict__ XT) {
  int i = blockIdx.x * 256 + threadIdx.x;
  if (i < 32768) {
    HTC[(i & 511) * 64 + (i >> 9)] = hidden[i];
  } else {
    int i2 = i - 32768;
    XT[(i2 & 127) * 64 + (i2 >> 7)] = dec_input[i2];
  }
}

// ---------------- K1: scores[b][s] = sum_h Wv[h]*tanh(hp[b][h]+ENCP[b][s][h]) ----------------
__global__ __launch_bounds__(1024) void k_scores(const u16* __restrict__ ENCP,
                                                 const float* __restrict__ HPT2,
                                                 const float* __restrict__ Wv,
                                                 float* __restrict__ SC) {
  const int tid = threadIdx.x, lane = tid & 63;
  const int wid = blockIdx.x * 16 + (tid >> 6);  // 0..4095
  const int b = wid >> 6;
  const int s0 = (wid & 63) << 3;
  float hp[8], wv[8];
  const float* hpb = HPT2 + (b << 9) + (lane << 3);
  *(float4*)hp       = *(const float4*)hpb;
  *(float4*)(hp + 4) = *(const float4*)(hpb + 4);
  *(float4*)wv       = *(const float4*)(Wv + (lane << 3));
  *(float4*)(wv + 4) = *(const float4*)(Wv + (lane << 3) + 4);
  const u16* base = ENCP + (((size_t)(b << 9) + s0) << 9) + (lane << 3);
  #pragma unroll
  for (int i = 0; i < 8; ++i) {
    u16x8 rv = *(const u16x8*)(base + ((size_t)i << 9));
    float acc = 0.f;
    #pragma unroll
    for (int r = 0; r < 8; ++r) acc += wv[r] * fast_tanh(hp[r] + bf2f(rv[r]));
    #pragma unroll
    for (int off = 32; off; off >>= 1) acc += __shfl_xor(acc, off);
    if (lane == 0) SC[(b << 9) + s0 + i] = acc;
  }
}

// ---------------- K2: softmax + context: CT[h][b] = sum_s w[s]*enc[b][s][h] ----------------
__global__ __launch_bounds__(1024) void k_ctx(const u16* __restrict__ ENCB,
                                              const float* __restrict__ SC,
                                              float* __restrict__ CT) {
  __shared__ float eL[512];
  __shared__ float cL[16 * 520];
  __shared__ float denL;
  const int b = blockIdx.x, tid = threadIdx.x, lane = tid & 63, w = tid >> 6;
  if (tid < 512) eL[tid] = __expf(SC[(b << 9) + tid]);  // |score| <= ~11: safe
  __syncthreads();
  if (tid < 64) {
    float d = 0.f;
    #pragma unroll
    for (int r = 0; r < 8; ++r) d += eL[tid + (r << 6)];
    #pragma unroll
    for (int off = 32; off; off >>= 1) d += __shfl_xor(d, off);
    if (tid == 0) denL = d;
  }
  __syncthreads();
  float c[8] = {};
  const u16* eb = ENCB + ((size_t)b << 18) + (lane << 3);
  #pragma unroll 8
  for (int i = 0; i < 32; ++i) {
    int s = w * 32 + i;
    float ev = eL[s];
    u16x8 rv = *(const u16x8*)(eb + ((size_t)s << 9));
    #pragma unroll
    for (int r = 0; r < 8; ++r) c[r] += ev * bf2f(rv[r]);
  }
  #pragma unroll
  for (int r = 0; r < 8; ++r) cL[w * 520 + (lane << 3) + r] = c[r];
  __syncthreads();
  if (tid < 512) {
    float inv = 1.f / denL;
    float v = 0.f;
    #pragma unroll
    for (int w2 = 0; w2 < 16; ++w2) v += cL[w2 * 520 + tid];
    CT[tid * 64 + b] = v * inv;
  }
}

// ---------------- K3: GRU gates + state update (in HTC) ----------------
__global__ __launch_bounds__(256) void k_gru(const float* __restrict__ XT,
                                             const float* __restrict__ CT,
                                             const float* __restrict__ Wih,
                                             const float* __restrict__ bih,
                                             const float* __restrict__ GHT,
                                             float* __restrict__ HTC) {
  __shared__ float cs[8192];
  const int tid = threadIdx.x, b = tid & 63;
  const int j = blockIdx.x * 4 + (tid >> 6);
  const float* wr = Wih + (size_t)j * KIH;
  const float* wz = Wih + (size_t)(j + 512) * KIH;
  const float* wn = Wih + (size_t)(j + 1024) * KIH;
  float gr = 0.f, gz = 0.f, gn = 0.f;
  #pragma unroll 4
  for (int k = 0; k < 128; ++k) {
    float x = XT[(k << 6) + b];
    gr += x * wr[k]; gz += x * wz[k]; gn += x * wn[k];
  }
  for (int tt = 0; tt < 4; ++tt) {
    const float4* src = (const float4*)(CT + tt * 8192);
    float4* dst = (float4*)cs;
    #pragma unroll
    for (int q = 0; q < 8; ++q) dst[tid + q * 256] = src[tid + q * 256];
    __syncthreads();
    const float* wrh = wr + 128 + tt * 128;
    const float* wzh = wz + 128 + tt * 128;
    const float* wnh = wn + 128 + tt * 128;
    #pragma unroll 4
    for (int hh = 0; hh < 128; ++hh) {
      float cc = cs[(hh << 6) + b];
      gr += cc * wrh[hh]; gz += cc * wzh[hh]; gn += cc * wnh[hh];
    }
    __syncthreads();
  }
  float r = fast_sig(gr + bih[j] + GHT[(j << 6) + b]);
  float z = fast_sig(gz + bih[j + 512] + GHT[((j + 512) << 6) + b]);
  float nn = fast_tanh(gn + bih[j + 1024] + r * GHT[((j + 1024) << 6) + b]);
  float h = HTC[(j << 6) + b];
  HTC[(j << 6) + b] = (1.f - z) * nn + z * h;
}

// ---------------- K4: projections from h: out/x, hproj, gh ----------------
__global__ __launch_bounds__(1024) void k_proj(const float* __restrict__ HTC,
                                               const float* __restrict__ Wout,
                                               const float* __restrict__ bout,
                                               const float* __restrict__ Wa,
                                               const float* __restrict__ Whh,
                                               const float* __restrict__ bhh,
                                               float* __restrict__ out,
                                               float* __restrict__ XT,
                                               float* __restrict__ HPT2,
                                               float* __restrict__ GHT, int t) {
  __shared__ float hs[16384];
  const int tid = threadIdx.x, b = tid & 63;
  const int n2 = blockIdx.x * 16 + (tid >> 6);  // 0..1087
  const float* w0;
  if (n2 < 128) w0 = Wout + (size_t)n2 * 512;
  else if (n2 < 640) w0 = Wa + (size_t)(n2 - 128) * 1024;
  else w0 = Whh + (size_t)(n2 - 640) * 512;
  const float* w1 = Whh + (size_t)(n2 + 448) * 512;
  float a0 = 0.f, a1 = 0.f;
  for (int kt = 0; kt < 2; ++kt) {
    float4* d4 = (float4*)hs;
    const float4* s4 = (const float4*)(HTC + kt * 16384);
    #pragma unroll
    for (int q = 0; q < 4; ++q) d4[tid + q * 1024] = s4[tid + q * 1024];
    __syncthreads();
    const float4* w04 = (const float4*)(w0 + kt * 256);
    const float4* w14 = (const float4*)(w1 + kt * 256);
    #pragma unroll 4
    for (int k4 = 0; k4 < 64; ++k4) {
      float4 v0 = w04[k4], v1 = w14[k4];
      float h0 = hs[((k4 * 4 + 0) << 6) + b];
      float h1 = hs[((k4 * 4 + 1) << 6) + b];
      float h2 = hs[((k4 * 4 + 2) << 6) + b];
      float h3 = hs[((k4 * 4 + 3) << 6) + b];
      a0 += h0 * v0.x + h1 * v0.y + h2 * v0.z + h3 * v0.w;
      a1 += h0 * v1.x + h1 * v1.y + h2 * v1.z + h3 * v1.w;
    }
    __syncthreads();
  }
  if (n2 < 128) {
    if (t >= 0) {
      float v = a0 + bout[n2];
      out[((size_t)b * T_ + t) * F_ + n2] = v;
      XT[(n2 << 6) + b] = v;
    }
  } else if (n2 < 640) {
    HPT2[((size_t)b << 9) + (n2 - 128)] = a0;
  } else {
    GHT[((n2 - 640) << 6) + b] = a0 + bhh[n2 - 640];
  }
  GHT[((n2 + 448) << 6) + b] = a1 + bhh[n2 + 448];
}

extern "C" void kernel_launch(void* const* d_in, const int* in_sizes, int n_in,
                              void* d_out, int out_size, void* d_ws, size_t ws_size,
                              hipStream_t stream) {
  const float* dec_input = (const float*)d_in[0];
  const float* hidden    = (const float*)d_in[1];
  const float* enc       = (const float*)d_in[2];
  // d_in[3] expected_outputs (unused), d_in[4] dec_output_len (fixed 96)
  const float* Wa   = (const float*)d_in[5];
  const float* ba   = (const float*)d_in[6];
  const float* Wv   = (const float*)d_in[7];
  // d_in[8] bv: constant shift, cancels in softmax
  const float* Wih  = (const float*)d_in[9];
  const float* bih  = (const float*)d_in[10];
  const float* Whh  = (const float*)d_in[11];
  const float* bhh  = (const float*)d_in[12];
  const float* Wout = (const float*)d_in[13];
  const float* bout = (const float*)d_in[14];
  float* out = (float*)d_out;

  char* ws = (char*)d_ws;
  float* HTC  = (float*)(ws + HTC_OFF);
  float* XT   = (float*)(ws + XT_OFF);
  float* HPT2 = (float*)(ws + HPT2_OFF);
  float* GHT  = (float*)(ws + GHT_OFF);
  float* CT   = (float*)(ws + CT_OFF);
  float* SC   = (float*)(ws + SC_OFF);
  u16* ENCP = (u16*)(ws + ENCP_OFF);
  u16* ENCB = (u16*)(ws + ENCB_OFF);

  hipLaunchKernelGGL(transcode_enc, dim3(4096), dim3(256), 0, stream, enc, ENCB);
  hipLaunchKernelGGL(gemm_bt_bf16, dim3(8, 8, 64), dim3(256), 0, stream,
                     enc, (long)(S_ * H_), H_, Wa + H_, 2 * H_, ba,
                     ENCP, (long)(S_ * H_), H_);
  hipLaunchKernelGGL(k0_init, dim3(160), dim3(256), 0, stream,
                     hidden, dec_input, HTC, XT);
  hipLaunchKernelGGL(k_proj, dim3(68), dim3(1024), 0, stream,
                     HTC, Wout, bout, Wa, Whh, bhh, out, XT, HPT2, GHT, -1);
  for (int t = 0; t < T_; ++t) {
    hipLaunchKernelGGL(k_scores, dim3(256), dim3(1024), 0, stream,
                       ENCP, HPT2, Wv, SC);
    hipLaunchKernelGGL(k_ctx, dim3(64), dim3(1024), 0, stream, ENCB, SC, CT);
    hipLaunchKernelGGL(k_gru, dim3(128), dim3(256), 0, stream,
                       XT, CT, Wih, bih, GHT, HTC);
    hipLaunchKernelGGL(k_proj, dim3(68), dim3(1024), 0, stream,
                       HTC, Wout, bout, Wa, Whh, bhh, out, XT, HPT2, GHT, t);
  }
}

// Round 4
// 8705.171 us; speedup vs baseline: 3.1980x; 1.0625x over previous
//
#include <hip/hip_runtime.h>

typedef unsigned short u16;
typedef u16 u16x8 __attribute__((ext_vector_type(8)));
typedef u16 u16x4 __attribute__((ext_vector_type(4)));
typedef short bf16x8 __attribute__((ext_vector_type(8)));
typedef float f32x4 __attribute__((ext_vector_type(4)));

#define B_   64
#define F_   128
#define H_   512
#define S_   512
#define T_   96
#define KIH  640

// ---- workspace byte offsets ----
#define HTC_OFF   0ul            // f32 [512][64]   h transposed
#define XT_OFF    131072ul       // f32 [128][64]   x transposed
#define HPT2_OFF  163840ul       // f32 [64][512]   h@Wa1^T
#define GHT_OFF   294912ul       // f32 [1536][64]  h@Whh^T + bhh
#define CTP_OFF   688128ul       // f32 [4][512][64] context partials
#define DEN_OFF   1212416ul      // f32 [4][64]     denominator partials
#define WB_OFF    1213440ul      // u16 [512][512]  Wa2 bf16
#define ENCP_OFF  2097152ul      // u16 [64][512][512] enc@Wa2^T + ba (bf16)
#define ENCB_OFF  35651584ul     // u16 [64][512][512] enc bf16
// end: 69206016 (~66 MiB)

__device__ __forceinline__ float bf2f(u16 u) {
  return __uint_as_float(((unsigned)u) << 16);
}
__device__ __forceinline__ u16 f2bf(float f) {
  unsigned u = __float_as_uint(f);
  return (u16)((u + 0x7fffu + ((u >> 16) & 1u)) >> 16);
}
__device__ __forceinline__ float fast_tanh(float x) {
  float e2 = __expf(2.f * x);
  return 1.f - 2.f / (e2 + 1.f);
}
__device__ __forceinline__ float fast_sig(float x) { return 1.f / (1.f + __expf(-x)); }

// ---------------- enc f32 -> bf16 (one-time) ----------------
__global__ __launch_bounds__(256) void transcode_enc(const float* __restrict__ enc,
                                                     u16* __restrict__ out) {
  int i = blockIdx.x * 256 + threadIdx.x;
  #pragma unroll
  for (int u = 0; u < 4; ++u) {
    int idx = i + u * 1048576;
    float4 v = ((const float4*)enc)[idx];
    u16x4 o;
    o[0] = f2bf(v.x); o[1] = f2bf(v.y); o[2] = f2bf(v.z); o[3] = f2bf(v.w);
    ((u16x4*)out)[idx] = o;
  }
}

// ---------------- Wa[:,H:] -> bf16 [512][512] (one-time) ----------------
__global__ __launch_bounds__(256) void transcode_wa(const float* __restrict__ Wa,
                                                    u16* __restrict__ WB) {
  int i = blockIdx.x * 256 + threadIdx.x;   // 65536 float4 groups
  int n = i >> 7, k4 = (i & 127) << 2;
  float4 v = *(const float4*)(Wa + (size_t)n * 1024 + 512 + k4);
  u16x4 o;
  o[0] = f2bf(v.x); o[1] = f2bf(v.y); o[2] = f2bf(v.z); o[3] = f2bf(v.w);
  *(u16x4*)(WB + (size_t)n * 512 + k4) = o;
}

// ---------------- MFMA GEMM: ENCP[m][n] = sum_k A[m][k]*B[n][k] + ba[n] ----------------
// M=32768, N=512, K=512; tiles 128x128, BK=32; 4 waves, each 32 rows x 128 cols.
__global__ __launch_bounds__(256) void mfma_encproj(const u16* __restrict__ Abf,
                                                    const u16* __restrict__ Bbf,
                                                    const float* __restrict__ ba,
                                                    u16* __restrict__ C) {
  __shared__ u16 As[128 * 40];
  __shared__ u16 Bs[128 * 40];
  const int tid = threadIdx.x, lane = tid & 63, w = tid >> 6;
  const int m0 = blockIdx.x << 7, n0 = blockIdx.y << 7;
  const int r0 = lane & 15, kh = lane >> 4;
  f32x4 acc[2][8] = {};
  for (int k0 = 0; k0 < 512; k0 += 32) {
    #pragma unroll
    for (int i = 0; i < 2; ++i) {
      int e = tid + (i << 8);
      int row = e >> 2, g = e & 3;
      *(u16x8*)&As[row * 40 + (g << 3)] =
          *(const u16x8*)(Abf + (size_t)(m0 + row) * 512 + k0 + (g << 3));
      *(u16x8*)&Bs[row * 40 + (g << 3)] =
          *(const u16x8*)(Bbf + (size_t)(n0 + row) * 512 + k0 + (g << 3));
    }
    __syncthreads();
    bf16x8 a[2], bb[8];
    #pragma unroll
    for (int r = 0; r < 2; ++r)
      a[r] = *(const bf16x8*)&As[((w << 5) + (r << 4) + r0) * 40 + (kh << 3)];
    #pragma unroll
    for (int c = 0; c < 8; ++c)
      bb[c] = *(const bf16x8*)&Bs[((c << 4) + r0) * 40 + (kh << 3)];
    #pragma unroll
    for (int r = 0; r < 2; ++r)
      #pragma unroll
      for (int c = 0; c < 8; ++c)
        acc[r][c] = __builtin_amdgcn_mfma_f32_16x16x32_bf16(a[r], bb[c], acc[r][c], 0, 0, 0);
    __syncthreads();
  }
  #pragma unroll
  for (int c = 0; c < 8; ++c) {
    int n = n0 + (c << 4) + r0;
    float bav = ba[n];
    #pragma unroll
    for (int r = 0; r < 2; ++r) {
      int mbase = m0 + (w << 5) + (r << 4) + (kh << 2);
      #pragma unroll
      for (int t = 0; t < 4; ++t)
        C[(size_t)(mbase + t) * 512 + n] = f2bf(acc[r][c][t] + bav);
    }
  }
}

// ---------------- init ----------------
__global__ __launch_bounds__(256) void k0_init(const float* __restrict__ hidden,
                                               const float* __restrict__ dec_input,
                                               float* __restrict__ HTC,
                                               float* __restrict__ XT) {
  int i = blockIdx.x * 256 + threadIdx.x;
  if (i < 32768) {
    HTC[(i & 511) * 64 + (i >> 9)] = hidden[i];
  } else {
    int i2 = i - 32768;
    XT[(i2 & 127) * 64 + (i2 >> 7)] = dec_input[i2];
  }
}

// ---------------- K1: fused scores + exp + partial context ----------------
__global__ __launch_bounds__(1024) void k_att(const u16* __restrict__ ENCP,
                                              const u16* __restrict__ ENCB,
                                              const float* __restrict__ HPT2,
                                              const float* __restrict__ Wv,
                                              float* __restrict__ CTpart,
                                              float* __restrict__ DENpart) {
  __shared__ float cL[16 * 520];
  __shared__ float dL[16];
  const int tid = threadIdx.x, lane = tid & 63, w = tid >> 6;
  const int b = blockIdx.x >> 2, sq = blockIdx.x & 3;
  float hp[8], wv[8];
  const float* hpb = HPT2 + (b << 9) + (lane << 3);
  *(float4*)hp       = *(const float4*)hpb;
  *(float4*)(hp + 4) = *(const float4*)(hpb + 4);
  *(float4*)wv       = *(const float4*)(Wv + (lane << 3));
  *(float4*)(wv + 4) = *(const float4*)(Wv + (lane << 3) + 4);
  const int s0 = (sq << 7) + (w << 3);
  const u16* pb = ENCP + (((size_t)(b << 9) + s0) << 9) + (lane << 3);
  const u16* eb = ENCB + (((size_t)(b << 9) + s0) << 9) + (lane << 3);
  float c[8] = {};
  float den = 0.f;
  #pragma unroll
  for (int i = 0; i < 8; ++i) {
    u16x8 pv = *(const u16x8*)(pb + ((size_t)i << 9));
    u16x8 ev = *(const u16x8*)(eb + ((size_t)i << 9));
    float acc = 0.f;
    #pragma unroll
    for (int r = 0; r < 8; ++r) acc += wv[r] * fast_tanh(hp[r] + bf2f(pv[r]));
    #pragma unroll
    for (int off = 32; off; off >>= 1) acc += __shfl_xor(acc, off);
    float e = __expf(acc);   // |score| <= ~11: safe un-normalized
    den += e;
    #pragma unroll
    for (int r = 0; r < 8; ++r) c[r] += e * bf2f(ev[r]);
  }
  *(float4*)&cL[w * 520 + (lane << 3)]     = *(float4*)c;
  *(float4*)&cL[w * 520 + (lane << 3) + 4] = *(float4*)(c + 4);
  if (lane == 0) dL[w] = den;
  __syncthreads();
  if (tid < 512) {
    float v = 0.f;
    #pragma unroll
    for (int w2 = 0; w2 < 16; ++w2) v += cL[w2 * 520 + tid];
    CTpart[(size_t)((sq << 9) + tid) * 64 + b] = v;
  } else if (tid < 576) {
    float d = (tid - 512 < 16) ? dL[tid - 512] : 0.f;
    #pragma unroll
    for (int off = 32; off; off >>= 1) d += __shfl_xor(d, off);
    if (tid == 512) DENpart[(sq << 6) + b] = d;
  }
}

// ---------------- K2: GRU gates + state update ----------------
__global__ __launch_bounds__(256) void k_gru(const float* __restrict__ XT,
                                             const float* __restrict__ CTpart,
                                             const float* __restrict__ DENpart,
                                             const float* __restrict__ Wih,
                                             const float* __restrict__ bih,
                                             const float* __restrict__ GHT,
                                             float* __restrict__ HTC) {
  __shared__ float cs[8192];
  const int tid = threadIdx.x, b = tid & 63;
  const int j = blockIdx.x * 4 + (tid >> 6);
  const float* wr = Wih + (size_t)j * KIH;
  const float* wz = wr + (size_t)512 * KIH;
  const float* wn = wr + (size_t)1024 * KIH;
  float grx = 0.f, gzx = 0.f, gnx = 0.f;
  #pragma unroll 4
  for (int k = 0; k < 128; ++k) {
    float x = XT[(k << 6) + b];
    grx += x * wr[k]; gzx += x * wz[k]; gnx += x * wn[k];
  }
  float grc = 0.f, gzc = 0.f, gnc = 0.f;
  for (int tt = 0; tt < 4; ++tt) {
    float4* dst = (float4*)cs;
    const float4* s0 = (const float4*)(CTpart + tt * 8192);
    const float4* s1 = (const float4*)(CTpart + 32768 + tt * 8192);
    const float4* s2 = (const float4*)(CTpart + 65536 + tt * 8192);
    const float4* s3 = (const float4*)(CTpart + 98304 + tt * 8192);
    #pragma unroll
    for (int q = 0; q < 8; ++q) {
      int i4 = tid + q * 256;
      float4 v = s0[i4], v1 = s1[i4], v2 = s2[i4], v3 = s3[i4];
      v.x += v1.x + v2.x + v3.x; v.y += v1.y + v2.y + v3.y;
      v.z += v1.z + v2.z + v3.z; v.w += v1.w + v2.w + v3.w;
      dst[i4] = v;
    }
    __syncthreads();
    const float* wrh = wr + 128 + tt * 128;
    const float* wzh = wz + 128 + tt * 128;
    const float* wnh = wn + 128 + tt * 128;
    #pragma unroll 4
    for (int hh = 0; hh < 128; ++hh) {
      float cc = cs[(hh << 6) + b];
      grc += cc * wrh[hh]; gzc += cc * wzh[hh]; gnc += cc * wnh[hh];
    }
    __syncthreads();
  }
  float inv = 1.f / (DENpart[b] + DENpart[64 + b] + DENpart[128 + b] + DENpart[192 + b]);
  float r = fast_sig(grx + grc * inv + bih[j] + GHT[(j << 6) + b]);
  float z = fast_sig(gzx + gzc * inv + bih[j + 512] + GHT[((j + 512) << 6) + b]);
  float nn = fast_tanh(gnx + gnc * inv + bih[j + 1024] + r * GHT[((j + 1024) << 6) + b]);
  float h = HTC[(j << 6) + b];
  HTC[(j << 6) + b] = (1.f - z) * nn + z * h;
}

// ---------------- K3: projections from h ----------------
__global__ __launch_bounds__(1024) void k_proj(const float* __restrict__ HTC,
                                               const float* __restrict__ Wout,
                                               const float* __restrict__ bout,
                                               const float* __restrict__ Wa,
                                               const float* __restrict__ Whh,
                                               const float* __restrict__ bhh,
                                               float* __restrict__ out,
                                               float* __restrict__ XT,
                                               float* __restrict__ HPT2,
                                               float* __restrict__ GHT, int t) {
  __shared__ float hs[16384];
  const int tid = threadIdx.x, b = tid & 63;
  const int n2 = blockIdx.x * 16 + (tid >> 6);  // 0..1087
  const float* w0;
  if (n2 < 128) w0 = Wout + (size_t)n2 * 512;
  else if (n2 < 640) w0 = Wa + (size_t)(n2 - 128) * 1024;
  else w0 = Whh + (size_t)(n2 - 640) * 512;
  const float* w1 = Whh + (size_t)(n2 + 448) * 512;
  float a0 = 0.f, a1 = 0.f;
  for (int kt = 0; kt < 2; ++kt) {
    float4* d4 = (float4*)hs;
    const float4* s4 = (const float4*)(HTC + kt * 16384);
    #pragma unroll
    for (int q = 0; q < 4; ++q) d4[tid + q * 1024] = s4[tid + q * 1024];
    __syncthreads();
    const float4* w04 = (const float4*)(w0 + kt * 256);
    const float4* w14 = (const float4*)(w1 + kt * 256);
    #pragma unroll 4
    for (int k4 = 0; k4 < 64; ++k4) {
      float4 v0 = w04[k4], v1 = w14[k4];
      float h0 = hs[((k4 * 4 + 0) << 6) + b];
      float h1 = hs[((k4 * 4 + 1) << 6) + b];
      float h2 = hs[((k4 * 4 + 2) << 6) + b];
      float h3 = hs[((k4 * 4 + 3) << 6) + b];
      a0 += h0 * v0.x + h1 * v0.y + h2 * v0.z + h3 * v0.w;
      a1 += h0 * v1.x + h1 * v1.y + h2 * v1.z + h3 * v1.w;
    }
    __syncthreads();
  }
  if (n2 < 128) {
    if (t >= 0) {
      float v = a0 + bout[n2];
      out[((size_t)b * T_ + t) * F_ + n2] = v;
      XT[(n2 << 6) + b] = v;
    }
  } else if (n2 < 640) {
    HPT2[((size_t)b << 9) + (n2 - 128)] = a0;
  } else {
    GHT[((n2 - 640) << 6) + b] = a0 + bhh[n2 - 640];
  }
  GHT[((n2 + 448) << 6) + b] = a1 + bhh[n2 + 448];
}

extern "C" void kernel_launch(void* const* d_in, const int* in_sizes, int n_in,
                              void* d_out, int out_size, void* d_ws, size_t ws_size,
                              hipStream_t stream) {
  const float* dec_input = (const float*)d_in[0];
  const float* hidden    = (const float*)d_in[1];
  const float* enc       = (const float*)d_in[2];
  const float* Wa   = (const float*)d_in[5];
  const float* ba   = (const float*)d_in[6];
  const float* Wv   = (const float*)d_in[7];
  // d_in[8] bv cancels in softmax
  const float* Wih  = (const float*)d_in[9];
  const float* bih  = (const float*)d_in[10];
  const float* Whh  = (const float*)d_in[11];
  const float* bhh  = (const float*)d_in[12];
  const float* Wout = (const float*)d_in[13];
  const float* bout = (const float*)d_in[14];
  float* out = (float*)d_out;

  char* ws = (char*)d_ws;
  float* HTC  = (float*)(ws + HTC_OFF);
  float* XT   = (float*)(ws + XT_OFF);
  float* HPT2 = (float*)(ws + HPT2_OFF);
  float* GHT  = (float*)(ws + GHT_OFF);
  float* CTP  = (float*)(ws + CTP_OFF);
  float* DEN  = (float*)(ws + DEN_OFF);
  u16* WB   = (u16*)(ws + WB_OFF);
  u16* ENCP = (u16*)(ws + ENCP_OFF);
  u16* ENCB = (u16*)(ws + ENCB_OFF);

  hipLaunchKernelGGL(transcode_enc, dim3(4096), dim3(256), 0, stream, enc, ENCB);
  hipLaunchKernelGGL(transcode_wa, dim3(256), dim3(256), 0, stream, Wa, WB);
  hipLaunchKernelGGL(mfma_encproj, dim3(256, 4), dim3(256), 0, stream,
                     ENCB, WB, ba, ENCP);
  hipLaunchKernelGGL(k0_init, dim3(160), dim3(256), 0, stream,
                     hidden, dec_input, HTC, XT);
  hipLaunchKernelGGL(k_proj, dim3(68), dim3(1024), 0, stream,
                     HTC, Wout, bout, Wa, Whh, bhh, out, XT, HPT2, GHT, -1);
  for (int t = 0; t < T_; ++t) {
    hipLaunchKernelGGL(k_att, dim3(256), dim3(1024), 0, stream,
                       ENCP, ENCB, HPT2, Wv, CTP, DEN);
    hipLaunchKernelGGL(k_gru, dim3(128), dim3(256), 0, stream,
                       XT, CTP, DEN, Wih, bih, GHT, HTC);
    hipLaunchKernelGGL(k_proj, dim3(68), dim3(1024), 0, stream,
                       HTC, Wout, bout, Wa, Whh, bhh, out, XT, HPT2, GHT, t);
  }
}